// Round 2
// baseline (161.077 us; speedup 1.0000x reference)
//
#include <hip/hip_runtime.h>

// Problem constants (from reference): B=16, L=512, D=512, T=4096, P=4
constexpr int Bn = 16;
constexpr int Ln = 512;
constexpr int Dn = 512;
constexpr int Tn = 4096;
constexpr int Pn = 4;

constexpr int D4     = Dn / 4;          // 128 float4 of encoder data per row
constexpr int ROW_F4 = (Dn + Pn) / 4;   // 129 float4 per output row
constexpr int NROWS  = Bn * Tn;         // 65536 output rows
constexpr int NXCD   = 8;

// ---------------------------------------------------------------------------
// K1: per-batch inclusive cumsum of durations -> cum[B][L] in workspace (32 KB).
// One block per batch, LDS Hillis-Steele scan. idx_map is gone: the fill
// kernel only needs total_b = cum[b][L-1]; the copy kernel only needs cum.
// ---------------------------------------------------------------------------
__global__ __launch_bounds__(Ln) void cum_kernel(
    const int* __restrict__ durations, int* __restrict__ cum_out) {
    const int b = blockIdx.x;
    const int l = threadIdx.x;

    __shared__ int cum[Ln];
    cum[l] = durations[b * Ln + l];
    __syncthreads();
    for (int off = 1; off < Ln; off <<= 1) {
        int v = (l >= off) ? cum[l - off] : 0;
        __syncthreads();
        cum[l] += v;
        __syncthreads();
    }
    cum_out[b * Ln + l] = cum[l];
}

// ---------------------------------------------------------------------------
// K2: fill kernel — zero D-part of invalid rows (t >= total_b, a contiguous
// per-batch tail, ~56% of rows) + fpos f4 for ALL rows. No idx_map, no enc:
// the zero path is structurally a pure fill (the thing the HW does at
// 6.7 TB/s). Block = 8 rows; row is wave-uniform -> the t>=total branch is
// wave-uniform; total is block-uniform (one scalar L2 load).
// ---------------------------------------------------------------------------
constexpr int THREADS   = 256;
constexpr int F4T       = 4;
constexpr int F4B       = THREADS * F4T;       // 1024 f4 = exactly 8 rows
constexpr int NBLK_FILL = NROWS * D4 / F4B;    // 8192
constexpr int BPX_FILL  = NBLK_FILL / NXCD;    // 1024

__global__ __launch_bounds__(THREADS) void fill_kernel(
    const float4* __restrict__ fpos4, const int* __restrict__ cum,
    float4* __restrict__ out4) {
    const int xcd  = blockIdx.x & (NXCD - 1);
    const int j    = blockIdx.x >> 3;
    const int blk  = xcd * BPX_FILL + j;
    const int base = blk * F4B + threadIdx.x;
    const int b    = blk >> 9;                 // 512 blocks per batch
    const int total = cum[b * Ln + (Ln - 1)];  // block-uniform

    #pragma unroll
    for (int h = 0; h < F4T; ++h) {
        const int g   = base + h * THREADS;
        const int row = g >> 7;                // wave-uniform
        const int t   = row & (Tn - 1);
        if (t >= total)                        // wave-uniform branch
            out4[g + row] = make_float4(0.f, 0.f, 0.f, 0.f);  // row*129 + c4
    }

    // fpos for ALL of this block's 8 rows (valid and invalid alike).
    if (threadIdx.x < 8) {
        const int r = blk * 8 + threadIdx.x;
        out4[r * ROW_F4 + (ROW_F4 - 1)] = fpos4[r];
    }
}

// ---------------------------------------------------------------------------
// K3: token-centric copy of the valid region. One wave owns one
// (token, half-row): it reads its 1-KB enc slice ONCE, then stores it to the
// token's `dur` consecutive output rows (dur = cum[j]-cum[j-1], 0..7,
// wave-uniform scalar loop — independent 1-KB coalesced stores, no per-row
// idx_map->enc dependency chain, enc read exactly once total = 16.8 MB).
// 2 tokens per 256-thread block (4 waves). XCD swizzle: 512 blocks/XCD =
// 2 batches -> that XCD's enc slice (2 MB) is L2-resident.
// ---------------------------------------------------------------------------
constexpr int NBLK_COPY = Bn * Ln / 2;        // 4096
constexpr int BPX_COPY  = NBLK_COPY / NXCD;   // 512

__global__ __launch_bounds__(THREADS) void copy_kernel(
    const float4* __restrict__ enc4, const int* __restrict__ cum,
    float4* __restrict__ out4) {
    const int xcd  = blockIdx.x & (NXCD - 1);
    const int j    = blockIdx.x >> 3;
    const int blk  = xcd * BPX_COPY + j;
    const int b    = blk >> 8;                 // 256 blocks per batch
    const int wave = threadIdx.x >> 6;
    const int lane = threadIdx.x & 63;
    const int tok  = ((blk & 255) << 1) + (wave >> 1);   // 0..511
    const int col  = ((wave & 1) << 6) + lane;           // 0..127

    int start = (tok == 0) ? 0 : cum[b * Ln + tok - 1];  // wave-uniform
    int end   = cum[b * Ln + tok];
    if (end > Tn) end = Tn;                    // safety clamp (never hit here)
    if (start >= end) return;                  // dur == 0 token

    const float4 v = enc4[(((b << 9) + tok) << 7) + col];

    const int rbase = b * Tn;
    for (int d = start; d < end; ++d)          // wave-uniform trip count <= 7
        out4[(rbase + d) * ROW_F4 + col] = v;
}

// ---------------------------------------------------------------------------
extern "C" void kernel_launch(void* const* d_in, const int* in_sizes, int n_in,
                              void* d_out, int out_size, void* d_ws, size_t ws_size,
                              hipStream_t stream) {
    const float* enc  = (const float*)d_in[0];  // [B, L, D] f32
    const int*   dur  = (const int*)d_in[1];    // [B, L] i32
    const float* fpos = (const float*)d_in[2];  // [B, T, P] f32
    // d_in[3] = input_lengths, unused by the reference computation

    float* out = (float*)d_out;                 // [B, T, D+P] f32
    int* cum = (int*)d_ws;                      // [B, L] i32 = 32 KB scratch

    cum_kernel<<<Bn, Ln, 0, stream>>>(dur, cum);

    static_assert(NBLK_FILL % NXCD == 0 && NBLK_COPY % NXCD == 0, "sizing");
    static_assert(F4B == 8 * D4, "fill block must cover exactly 8 rows");

    fill_kernel<<<NBLK_FILL, THREADS, 0, stream>>>(
        (const float4*)fpos, cum, (float4*)out);
    copy_kernel<<<NBLK_COPY, THREADS, 0, stream>>>(
        (const float4*)enc, cum, (float4*)out);
}

// Round 3
// 154.813 us; speedup vs baseline: 1.0405x; 1.0405x over previous
//
#include <hip/hip_runtime.h>

// Problem constants (from reference): B=16, L=512, D=512, T=4096, P=4
constexpr int Bn = 16;
constexpr int Ln = 512;
constexpr int Dn = 512;
constexpr int Tn = 4096;
constexpr int Pn = 4;

constexpr int D4     = Dn / 4;          // 128 float4 of encoder data per row
constexpr int ROW_F4 = (Dn + Pn) / 4;   // 129 float4 per output row
constexpr int NROWS  = Bn * Tn;         // 65536 output rows
constexpr int NXCD   = 8;
constexpr int THREADS = 256;

// Copy role: 2 tokens per block (4 waves: wave pair per token, half-row each).
constexpr int NBLK_COPY = Bn * Ln / 2;        // 4096
constexpr int BPX_COPY  = NBLK_COPY / NXCD;   // 512  (= 2 batches per XCD)

// Fill role: 8 output rows (D-part) per block, 4 f4/thread.
constexpr int F4T       = 4;
constexpr int F4B       = THREADS * F4T;      // 1024 f4 = exactly 8 rows
constexpr int NBLK_FILL = NROWS * D4 / F4B;   // 8192
constexpr int BPX_FILL  = NBLK_FILL / NXCD;   // 1024 (= 2 batches per XCD)

constexpr int NBLK = NBLK_COPY + NBLK_FILL;   // 12288 — ONE dispatch

// ---------------------------------------------------------------------------
// Single fused kernel. No cum kernel, no workspace, no inter-kernel drains:
// each block derives the prefix-sum info it needs from durations (32 KB,
// L2-resident; ~24 MB of redundant L2 reads total — free at 34 TB/s).
//   gid < NBLK_COPY : token-centric copy. Masked block reduction gives
//       S = sum_{l<tok0} dur[l]; two scalar reads give both tokens' spans.
//       Wave reads its 1-KB enc half-row ONCE, stores it to `dur` rows.
//   gid >= NBLK_COPY: fill. Full block reduction gives total_b; zero the
//       D-part of the invalid tail rows + write fpos f4 for all 8 rows.
// Copy blocks first: their read->store latency chain starts earliest.
// Both roles keep the XCD swizzle (2 batches per XCD -> enc L2-resident).
// Write sets are disjoint at 16B granularity; all output bytes written once.
// ---------------------------------------------------------------------------
__global__ __launch_bounds__(THREADS) void fused_kernel(
    const float4* __restrict__ enc4, const float4* __restrict__ fpos4,
    const int* __restrict__ dur, float4* __restrict__ out4) {
    __shared__ int s_red[4];
    const int tid  = threadIdx.x;
    const int wave = tid >> 6;
    const int lane = tid & 63;
    const int gid  = blockIdx.x;

    if (gid < NBLK_COPY) {
        // ---------------- copy role ----------------
        const int xcd  = gid & (NXCD - 1);
        const int j    = gid >> 3;
        const int blk  = xcd * BPX_COPY + j;
        const int b    = blk >> 8;                 // 256 copy blocks / batch
        const int tok0 = (blk & 255) << 1;         // tokens tok0, tok0+1
        const int* db  = dur + b * Ln;

        // S = sum_{l < tok0} dur[l]  (masked block reduction)
        int acc = 0;
        if (tid < tok0)       acc += db[tid];
        if (tid + 256 < tok0) acc += db[tid + 256];
        #pragma unroll
        for (int off = 32; off; off >>= 1) acc += __shfl_xor(acc, off);
        if (lane == 0) s_red[wave] = acc;
        __syncthreads();
        const int S  = s_red[0] + s_red[1] + s_red[2] + s_red[3];
        const int d0 = db[tok0];
        const int d1 = db[tok0 + 1];

        const int tp  = wave >> 1;                 // which of the 2 tokens
        const int tok = tok0 + tp;
        const int col = ((wave & 1) << 6) | lane;  // 0..127
        int start = S + (tp ? d0 : 0);             // wave-uniform
        int end   = start + (tp ? d1 : d0);
        if (end > Tn) end = Tn;                    // safety clamp
        if (start < end) {
            const float4 v = enc4[(((b << 9) + tok) << 7) + col];
            const int rbase = b * Tn;
            for (int d = start; d < end; ++d)      // uniform trip count <= 7
                out4[(rbase + d) * ROW_F4 + col] = v;
        }
    } else {
        // ---------------- fill role ----------------
        const int g2  = gid - NBLK_COPY;
        const int xcd = g2 & (NXCD - 1);
        const int j   = g2 >> 3;
        const int blk = xcd * BPX_FILL + j;
        const int b   = blk >> 9;                  // 512 fill blocks / batch
        const int* db = dur + b * Ln;

        // total_b = sum of all 512 durations (full block reduction)
        int acc = db[tid] + db[tid + 256];
        #pragma unroll
        for (int off = 32; off; off >>= 1) acc += __shfl_xor(acc, off);
        if (lane == 0) s_red[wave] = acc;
        __syncthreads();
        const int total = s_red[0] + s_red[1] + s_red[2] + s_red[3];

        const int base = blk * F4B + tid;
        #pragma unroll
        for (int h = 0; h < F4T; ++h) {
            const int g   = base + h * THREADS;
            const int row = g >> 7;                // wave-uniform
            const int t   = row & (Tn - 1);
            if (t >= total)                        // wave-uniform branch
                out4[g + row] = make_float4(0.f, 0.f, 0.f, 0.f); // row*129+c4
        }

        // fpos f4 for all 8 of this block's rows (valid and invalid alike).
        if (tid < 8) {
            const int r = blk * 8 + tid;
            out4[r * ROW_F4 + (ROW_F4 - 1)] = fpos4[r];
        }
    }
}

// ---------------------------------------------------------------------------
extern "C" void kernel_launch(void* const* d_in, const int* in_sizes, int n_in,
                              void* d_out, int out_size, void* d_ws, size_t ws_size,
                              hipStream_t stream) {
    const float* enc  = (const float*)d_in[0];  // [B, L, D] f32
    const int*   dur  = (const int*)d_in[1];    // [B, L] i32
    const float* fpos = (const float*)d_in[2];  // [B, T, P] f32
    // d_in[3] = input_lengths, unused by the reference computation
    float* out = (float*)d_out;                 // [B, T, D+P] f32
    // workspace unused — single self-contained dispatch

    static_assert(NBLK_COPY % NXCD == 0 && NBLK_FILL % NXCD == 0, "sizing");
    static_assert(F4B == 8 * D4, "fill block must cover exactly 8 rows");

    fused_kernel<<<NBLK, THREADS, 0, stream>>>(
        (const float4*)enc, (const float4*)fpos, dur, (float4*)out);
}